// Round 15
// baseline (96.288 us; speedup 1.0000x reference)
//
#include <hip/hip_runtime.h>
#include <hip/hip_bf16.h>

typedef float f32x4 __attribute__((ext_vector_type(4)));

#define NROWS 8192
#define HALF_N 4096
#define DIM 128
#define C1 14.42695040888963f    /* (1/T) * log2(e) */
#define LN2 0.6931471805599453f
#define GBLK 1024                /* 64 row-quads x 16 col-splits */

/* fp8 packed MFMA-operand layout (R14-verified, absmax 0): rows in groups of
   16; group g (2048 B) holds rows [g*16,+16). Within a group: 4 ks-regions of
   512 B; byte lane*8 of region ks = 8-value k-chunk of row (g*16+(lane&15)).
   One wave fragment load = one fully-coalesced 512 B global_load_dwordx2.
   A and B share the mapping so intra-dot k-permutations cancel. */

// ---- kernel 1: normalize (i,j) pairs -> packA(=rn*C1 fp8), packB(=rn fp8) --
__global__ __launch_bounds__(256) void k_normalize(
    const float* __restrict__ zi, const float* __restrict__ zj,
    char* __restrict__ packA, char* __restrict__ packB,
    float* __restrict__ rowsum, float* __restrict__ pbuf,
    unsigned int* __restrict__ done)
{
    const int wave = threadIdx.x >> 6;
    const int lane = threadIdx.x & 63;
    const int ks_  = lane >> 4;
    const int qr_  = (lane >> 2) & 3;
    const int rem_ = (lane & 3) * 2;          // byte pos of this lane's 2 vals
    #pragma unroll
    for (int t = 0; t < 2; ++t) {
        const int idx = blockIdx.x * 8 + wave * 2 + t;   // i-row; partner idx+N
        float2 vi = *(const float2*)(zi + (size_t)idx * DIM + lane * 2);
        float2 vj = *(const float2*)(zj + (size_t)idx * DIM + lane * 2);
        float ssi = vi.x * vi.x + vi.y * vi.y;
        float ssj = vj.x * vj.x + vj.y * vj.y;
        float cr  = vi.x * vj.x + vi.y * vj.y;
        #pragma unroll
        for (int m = 32; m >= 1; m >>= 1) {
            ssi += __shfl_xor(ssi, m, 64);
            ssj += __shfl_xor(ssj, m, 64);
            cr  += __shfl_xor(cr,  m, 64);
        }
        const float sci = 1.0f / fmaxf(sqrtf(ssi), 1e-8f);
        const float scj = 1.0f / fmaxf(sqrtf(ssj), 1e-8f);
        #pragma unroll
        for (int h = 0; h < 2; ++h) {                 // h=0: i-row, h=1: j-row
            const int   row = idx + h * HALF_N;
            const float sx  = h ? vj.x * scj : vi.x * sci;
            const float sy  = h ? vj.y * scj : vi.y * sci;
            const size_t off = (size_t)(row >> 4) * 2048 + ks_ * 512
                             + (qr_ * 16 + (row & 15)) * 8 + rem_;
            unsigned ua = __builtin_amdgcn_cvt_pk_fp8_f32(sx * C1, sy * C1, 0, false);
            unsigned ub = __builtin_amdgcn_cvt_pk_fp8_f32(sx,      sy,      0, false);
            *(unsigned short*)(packA + off) = (unsigned short)ua;
            *(unsigned short*)(packB + off) = (unsigned short)ub;
        }
        if (lane == 0) {
            const float p = cr * sci * scj;   // exact f32 positive-pair cosine
            pbuf[idx] = p;
            pbuf[idx + HALF_N] = p;
        }
    }
    if (threadIdx.x < 16) rowsum[blockIdx.x * 16 + threadIdx.x] = 0.0f;
    if (blockIdx.x == 0 && threadIdx.x == 0) *done = 0u;
}

// ---- kernel 2: dual-strip fp8 sim GEMM + exp rowsum + finalize -------------
// ILP experiment: each wave = 32 rows x TWO independent 256-col strips.
// 8 outstanding loads/step + two independent MFMA->exp2 chains per wave
// (R8-R14: single-chain variants all plateau 40-53 us at <15% pipe util
// regardless of occupancy/bytes -> exposed per-step L2 latency is the wall).
__global__ __launch_bounds__(256, 4) void k_gemm(
    const char* __restrict__ packA, const char* __restrict__ packB,
    float* __restrict__ rowsum, const float* __restrict__ pbuf,
    unsigned int* __restrict__ done, float* __restrict__ out)
{
    const int wave = threadIdx.x >> 6;
    const int lane = threadIdx.x & 63;
    const int qrow = lane >> 4, lcol = lane & 15;
    const int cv = blockIdx.x & 15;                   // 16 col-splits of 512
    const int rg = (blockIdx.x >> 4) * 4 + wave;      // 256 row-groups of 32

    // A fragments: 8 coalesced 512 B loads (rows rg*32..+31, all K)
    long afrag[2][4];
    #pragma unroll
    for (int mi = 0; mi < 2; ++mi)
        #pragma unroll
        for (int ks = 0; ks < 4; ++ks)
            afrag[mi][ks] = *(const long*)(packA
                + (size_t)(rg * 2 + mi) * 2048 + ks * 512 + lane * 8);

    float rsum[2][4];
    #pragma unroll
    for (int mi = 0; mi < 2; ++mi)
        #pragma unroll
        for (int r = 0; r < 4; ++r) rsum[mi][r] = 0.0f;

    // two independent B strips: cols [cv*512, +256) and [cv*512+256, +256)
    const char* Bb0 = packB + (size_t)(cv * 32) * 2048 + lane * 8;
    const char* Bb1 = Bb0 + (size_t)16 * 2048;

    #pragma unroll 1
    for (int s = 0; s < 16; ++s) {                    // 16 steps of 16+16 cols
        const char* bp0 = Bb0 + (size_t)s * 2048;
        const char* bp1 = Bb1 + (size_t)s * 2048;
        long bf0[4], bf1[4];
        #pragma unroll
        for (int ks = 0; ks < 4; ++ks) {
            bf0[ks] = *(const long*)(bp0 + ks * 512);
            bf1[ks] = *(const long*)(bp1 + ks * 512);
        }

        f32x4 acc[2][2];
        const f32x4 zero = {0.0f, 0.0f, 0.0f, 0.0f};
        #pragma unroll
        for (int mi = 0; mi < 2; ++mi) { acc[mi][0] = zero; acc[mi][1] = zero; }
        #pragma unroll
        for (int ks = 0; ks < 4; ++ks)
            #pragma unroll
            for (int mi = 0; mi < 2; ++mi) {
                acc[mi][0] = __builtin_amdgcn_mfma_f32_16x16x32_fp8_fp8(
                    afrag[mi][ks], bf0[ks], acc[mi][0], 0, 0, 0);
                acc[mi][1] = __builtin_amdgcn_mfma_f32_16x16x32_fp8_fp8(
                    afrag[mi][ks], bf1[ks], acc[mi][1], 0, 0, 0);
            }

        // rowsum += 2^(s*C1) from both strips (acc holds s*C1 via packA)
        #pragma unroll
        for (int mi = 0; mi < 2; ++mi)
            #pragma unroll
            for (int r = 0; r < 4; ++r)
                rsum[mi][r] += __builtin_amdgcn_exp2f(acc[mi][0][r])
                             + __builtin_amdgcn_exp2f(acc[mi][1][r]);
    }

    // reduce over the 16 col-lanes, one atomic per row
    #pragma unroll
    for (int mi = 0; mi < 2; ++mi)
        #pragma unroll
        for (int r = 0; r < 4; ++r) {
            float v = rsum[mi][r];
            v += __shfl_xor(v, 1, 64);
            v += __shfl_xor(v, 2, 64);
            v += __shfl_xor(v, 4, 64);
            v += __shfl_xor(v, 8, 64);
            if (lcol == 0)
                atomicAdd(&rowsum[rg * 32 + mi * 16 + qrow * 4 + r], v);
        }

    // ---- last-block finalize; no producer-side fence (R11-R14 validated) ---
    __syncthreads();            // compiler drains vmcnt(0) before s_barrier
    __shared__ int is_last;
    if (threadIdx.x == 0) {
        unsigned old = __hip_atomic_fetch_add(done, 1u, __ATOMIC_RELAXED,
                                              __HIP_MEMORY_SCOPE_AGENT);
        is_last = (old == GBLK - 1);
    }
    __syncthreads();
    if (!is_last) return;
    __threadfence();            // acquire side only, once

    // loss_k = (log2(rowsum_k + 2^(p*C1)) - p*C1) * ln2   [v_log_f32 is LOG2]
    float lsum = 0.0f;
    for (int r = threadIdx.x; r < NROWS; r += 256) {
        float rs = __hip_atomic_load(&rowsum[r], __ATOMIC_RELAXED, __HIP_MEMORY_SCOPE_AGENT);
        float pc = pbuf[r] * C1;
        float S  = rs + __builtin_amdgcn_exp2f(pc);
        lsum += (__builtin_amdgcn_logf(S) - pc) * LN2;
    }
    #pragma unroll
    for (int m = 32; m >= 1; m >>= 1) lsum += __shfl_xor(lsum, m, 64);
    __shared__ float part[4];
    if (lane == 0) part[wave] = lsum;
    __syncthreads();
    if (threadIdx.x == 0)
        out[0] = (part[0] + part[1] + part[2] + part[3]) * (1.0f / (float)NROWS);
}

extern "C" void kernel_launch(void* const* d_in, const int* in_sizes, int n_in,
                              void* d_out, int out_size, void* d_ws, size_t ws_size,
                              hipStream_t stream)
{
    const float* zi = (const float*)d_in[0];
    const float* zj = (const float*)d_in[1];
    float* out = (float*)d_out;

    // ws: packA 1MB | packB 1MB | rowsum f32[8192] | pbuf f32[8192] | done
    char*  packA  = (char*)d_ws;
    char*  packB  = packA + (size_t)NROWS * 128;
    float* rowsum = (float*)(packB + (size_t)NROWS * 128);
    float* pbuf   = rowsum + NROWS;
    unsigned int* done = (unsigned int*)(pbuf + NROWS);

    k_normalize<<<NROWS / 16, 256, 0, stream>>>(zi, zj, packA, packB, rowsum, pbuf, done);
    k_gemm<<<GBLK, 256, 0, stream>>>(packA, packB, rowsum, pbuf, done, out);
}

// Round 16
// 93.523 us; speedup vs baseline: 1.0296x; 1.0296x over previous
//
#include <hip/hip_runtime.h>
#include <hip/hip_bf16.h>

typedef float f32x4 __attribute__((ext_vector_type(4)));

#define NROWS 8192
#define HALF_N 4096
#define DIM 128
#define C1 14.42695040888963f    /* (1/T) * log2(e) */
#define LN2 0.6931471805599453f
#define GBLK 1024                /* 32 rg-quads x 32 col-splits */

/* fp8 packed MFMA-operand layout (R14-verified, absmax 0): rows in groups of
   16; group g (2048 B) holds rows [g*16,+16). Within a group: 4 ks-regions of
   512 B; byte lane*8 of region ks = 8-value k-chunk of row (g*16+(lane&15)).
   One wave fragment load = one fully-coalesced 512 B global_load_dwordx2.
   A and B share the mapping so intra-dot k-permutations cancel. */

// ---- kernel 1: normalize (i,j) pairs -> packA(=rn*C1 fp8), packB(=rn fp8) --
__global__ __launch_bounds__(256) void k_normalize(
    const float* __restrict__ zi, const float* __restrict__ zj,
    char* __restrict__ packA, char* __restrict__ packB,
    float* __restrict__ rowsum, float* __restrict__ pbuf,
    unsigned int* __restrict__ done)
{
    const int wave = threadIdx.x >> 6;
    const int lane = threadIdx.x & 63;
    const int ks_  = lane >> 4;
    const int qr_  = (lane >> 2) & 3;
    const int rem_ = (lane & 3) * 2;          // byte pos of this lane's 2 vals
    #pragma unroll
    for (int t = 0; t < 2; ++t) {
        const int idx = blockIdx.x * 8 + wave * 2 + t;   // i-row; partner idx+N
        float2 vi = *(const float2*)(zi + (size_t)idx * DIM + lane * 2);
        float2 vj = *(const float2*)(zj + (size_t)idx * DIM + lane * 2);
        float ssi = vi.x * vi.x + vi.y * vi.y;
        float ssj = vj.x * vj.x + vj.y * vj.y;
        float cr  = vi.x * vj.x + vi.y * vj.y;
        #pragma unroll
        for (int m = 32; m >= 1; m >>= 1) {
            ssi += __shfl_xor(ssi, m, 64);
            ssj += __shfl_xor(ssj, m, 64);
            cr  += __shfl_xor(cr,  m, 64);
        }
        const float sci = 1.0f / fmaxf(sqrtf(ssi), 1e-8f);
        const float scj = 1.0f / fmaxf(sqrtf(ssj), 1e-8f);
        #pragma unroll
        for (int h = 0; h < 2; ++h) {                 // h=0: i-row, h=1: j-row
            const int   row = idx + h * HALF_N;
            const float sx  = h ? vj.x * scj : vi.x * sci;
            const float sy  = h ? vj.y * scj : vi.y * sci;
            const size_t off = (size_t)(row >> 4) * 2048 + ks_ * 512
                             + (qr_ * 16 + (row & 15)) * 8 + rem_;
            unsigned ua = __builtin_amdgcn_cvt_pk_fp8_f32(sx * C1, sy * C1, 0, false);
            unsigned ub = __builtin_amdgcn_cvt_pk_fp8_f32(sx,      sy,      0, false);
            *(unsigned short*)(packA + off) = (unsigned short)ua;
            *(unsigned short*)(packB + off) = (unsigned short)ub;
        }
        if (lane == 0) {
            const float p = cr * sci * scj;   // exact f32 positive-pair cosine
            pbuf[idx] = p;
            pbuf[idx + HALF_N] = p;
        }
    }
    if (threadIdx.x < 16) rowsum[blockIdx.x * 16 + threadIdx.x] = 0.0f;
    if (blockIdx.x == 0 && threadIdx.x == 0) *done = 0u;
}

// ---- kernel 2: fp8 sim GEMM + exp rowsum + finalize. MLP experiment --------
// R14's proven body (absmax 0) with exactly three deltas:
//  (1) #pragma unroll 4 on the step loop -> compiler may hoist 16 B-loads
//      (8 KB/wave in flight, 4x R14) across the latency window;
//  (2) __launch_bounds__(256,2) -> 256-VGPR cap so the unroll doesn't spill
//      (R3's failure mode at default bounds);
//  (3) nothing else. Theory: every design R8-R15 is bound by in-flight-bytes
//      x cold-L2 (post-kernel flush) L3 latency ~800cyc -> ~10-20 B/cyc/CU;
//      retrodicts R12=42us, R13=86us, R14~41us, R15~40us quantitatively.
__global__ __launch_bounds__(256, 2) void k_gemm(
    const char* __restrict__ packA, const char* __restrict__ packB,
    float* __restrict__ rowsum, const float* __restrict__ pbuf,
    unsigned int* __restrict__ done, float* __restrict__ out)
{
    const int wave = threadIdx.x >> 6;
    const int lane = threadIdx.x & 63;
    const int qrow = lane >> 4, lcol = lane & 15;
    const int cv = blockIdx.x & 31;                   // 32 col-splits of 256
    const int rg = (blockIdx.x >> 5) * 4 + wave;      // 128 row-groups of 64

    // A fragments: 16 coalesced 512 B loads (rows rg*64..+63, all K), 32 VGPR
    long afrag[4][4];
    #pragma unroll
    for (int mi = 0; mi < 4; ++mi)
        #pragma unroll
        for (int ks = 0; ks < 4; ++ks)
            afrag[mi][ks] = *(const long*)(packA
                + (size_t)(rg * 4 + mi) * 2048 + ks * 512 + lane * 8);

    float rsum[4][4];
    #pragma unroll
    for (int mi = 0; mi < 4; ++mi)
        #pragma unroll
        for (int r = 0; r < 4; ++r) rsum[mi][r] = 0.0f;

    const char* Bb = packB + (size_t)(cv * 16) * 2048 + lane * 8;

    #pragma unroll 4
    for (int s = 0; s < 16; ++s) {                    // 16 steps of 16 cols
        const char* bp = Bb + (size_t)s * 2048;
        long bfrag[4];
        #pragma unroll
        for (int ks = 0; ks < 4; ++ks)
            bfrag[ks] = *(const long*)(bp + ks * 512);

        f32x4 acc[4];
        const f32x4 zero = {0.0f, 0.0f, 0.0f, 0.0f};
        #pragma unroll
        for (int mi = 0; mi < 4; ++mi) acc[mi] = zero;
        #pragma unroll
        for (int ks = 0; ks < 4; ++ks)
            #pragma unroll
            for (int mi = 0; mi < 4; ++mi)
                acc[mi] = __builtin_amdgcn_mfma_f32_16x16x32_fp8_fp8(
                    afrag[mi][ks], bfrag[ks], acc[mi], 0, 0, 0);

        // rowsum += 2^(s*C1); acc already holds s*C1 via pre-scaled A
        #pragma unroll
        for (int mi = 0; mi < 4; ++mi)
            #pragma unroll
            for (int r = 0; r < 4; ++r)
                rsum[mi][r] += __builtin_amdgcn_exp2f(acc[mi][r]);
    }

    // reduce over the 16 col-lanes, one atomic per row
    #pragma unroll
    for (int mi = 0; mi < 4; ++mi)
        #pragma unroll
        for (int r = 0; r < 4; ++r) {
            float v = rsum[mi][r];
            v += __shfl_xor(v, 1, 64);
            v += __shfl_xor(v, 2, 64);
            v += __shfl_xor(v, 4, 64);
            v += __shfl_xor(v, 8, 64);
            if (lcol == 0)
                atomicAdd(&rowsum[rg * 64 + mi * 16 + qrow * 4 + r], v);
        }

    // ---- last-block finalize; no producer-side fence (R11-R15 validated) ---
    __syncthreads();            // compiler drains vmcnt(0) before s_barrier
    __shared__ int is_last;
    if (threadIdx.x == 0) {
        unsigned old = __hip_atomic_fetch_add(done, 1u, __ATOMIC_RELAXED,
                                              __HIP_MEMORY_SCOPE_AGENT);
        is_last = (old == GBLK - 1);
    }
    __syncthreads();
    if (!is_last) return;
    __threadfence();            // acquire side only, once

    // loss_k = (log2(rowsum_k + 2^(p*C1)) - p*C1) * ln2   [v_log_f32 is LOG2]
    float lsum = 0.0f;
    for (int r = threadIdx.x; r < NROWS; r += 256) {
        float rs = __hip_atomic_load(&rowsum[r], __ATOMIC_RELAXED, __HIP_MEMORY_SCOPE_AGENT);
        float pc = pbuf[r] * C1;
        float S  = rs + __builtin_amdgcn_exp2f(pc);
        lsum += (__builtin_amdgcn_logf(S) - pc) * LN2;
    }
    #pragma unroll
    for (int m = 32; m >= 1; m >>= 1) lsum += __shfl_xor(lsum, m, 64);
    __shared__ float part[4];
    if (lane == 0) part[wave] = lsum;
    __syncthreads();
    if (threadIdx.x == 0)
        out[0] = (part[0] + part[1] + part[2] + part[3]) * (1.0f / (float)NROWS);
}

extern "C" void kernel_launch(void* const* d_in, const int* in_sizes, int n_in,
                              void* d_out, int out_size, void* d_ws, size_t ws_size,
                              hipStream_t stream)
{
    const float* zi = (const float*)d_in[0];
    const float* zj = (const float*)d_in[1];
    float* out = (float*)d_out;

    // ws: packA 1MB | packB 1MB | rowsum f32[8192] | pbuf f32[8192] | done
    char*  packA  = (char*)d_ws;
    char*  packB  = packA + (size_t)NROWS * 128;
    float* rowsum = (float*)(packB + (size_t)NROWS * 128);
    float* pbuf   = rowsum + NROWS;
    unsigned int* done = (unsigned int*)(pbuf + NROWS);

    k_normalize<<<NROWS / 16, 256, 0, stream>>>(zi, zj, packA, packB, rowsum, pbuf, done);
    k_gemm<<<GBLK, 256, 0, stream>>>(packA, packB, rowsum, pbuf, done, out);
}

// Round 17
// 90.711 us; speedup vs baseline: 1.0615x; 1.0310x over previous
//
#include <hip/hip_runtime.h>
#include <hip/hip_bf16.h>

typedef float f32x4 __attribute__((ext_vector_type(4)));

#define NROWS 8192
#define HALF_N 4096
#define DIM 128
#define C1 14.42695040888963f    /* (1/T) * log2(e) */
#define LN2 0.6931471805599453f
#define NSTRIP 2112              /* triangle strips: sum_q 4*(32-q) */
#define GBLK (NSTRIP / 4)        /* 528 blocks, 4 strips (waves) each */

/* fp8 packed MFMA-operand layout (R14-verified, absmax 0): rows in groups of
   16; group g (2048 B) holds rows [g*16,+16). Within a group: 4 ks-regions of
   512 B; byte lane*8 of region ks = 8-value k-chunk of row (g*16+(lane&15)).
   One wave fragment load = one fully-coalesced 512 B global_load_dwordx2.
   A and B share the mapping so intra-dot k-permutations cancel. */

// ---- kernel 1: normalize (i,j) pairs -> packA(=rn*C1 fp8), packB(=rn fp8) --
__global__ __launch_bounds__(256) void k_normalize(
    const float* __restrict__ zi, const float* __restrict__ zj,
    char* __restrict__ packA, char* __restrict__ packB,
    float* __restrict__ rowsum, float* __restrict__ pbuf,
    unsigned int* __restrict__ done)
{
    const int wave = threadIdx.x >> 6;
    const int lane = threadIdx.x & 63;
    const int ks_  = lane >> 4;
    const int qr_  = (lane >> 2) & 3;
    const int rem_ = (lane & 3) * 2;          // byte pos of this lane's 2 vals
    #pragma unroll
    for (int t = 0; t < 2; ++t) {
        const int idx = blockIdx.x * 8 + wave * 2 + t;   // i-row; partner idx+N
        float2 vi = *(const float2*)(zi + (size_t)idx * DIM + lane * 2);
        float2 vj = *(const float2*)(zj + (size_t)idx * DIM + lane * 2);
        float ssi = vi.x * vi.x + vi.y * vi.y;
        float ssj = vj.x * vj.x + vj.y * vj.y;
        float cr  = vi.x * vj.x + vi.y * vj.y;
        #pragma unroll
        for (int m = 32; m >= 1; m >>= 1) {
            ssi += __shfl_xor(ssi, m, 64);
            ssj += __shfl_xor(ssj, m, 64);
            cr  += __shfl_xor(cr,  m, 64);
        }
        const float sci = 1.0f / fmaxf(sqrtf(ssi), 1e-8f);
        const float scj = 1.0f / fmaxf(sqrtf(ssj), 1e-8f);
        #pragma unroll
        for (int h = 0; h < 2; ++h) {                 // h=0: i-row, h=1: j-row
            const int   row = idx + h * HALF_N;
            const float sx  = h ? vj.x * scj : vi.x * sci;
            const float sy  = h ? vj.y * scj : vi.y * sci;
            const size_t off = (size_t)(row >> 4) * 2048 + ks_ * 512
                             + (qr_ * 16 + (row & 15)) * 8 + rem_;
            unsigned ua = __builtin_amdgcn_cvt_pk_fp8_f32(sx * C1, sy * C1, 0, false);
            unsigned ub = __builtin_amdgcn_cvt_pk_fp8_f32(sx,      sy,      0, false);
            *(unsigned short*)(packA + off) = (unsigned short)ua;
            *(unsigned short*)(packB + off) = (unsigned short)ub;
        }
        if (lane == 0) {
            const float p = cr * sci * scj;   // exact f32 positive-pair cosine
            pbuf[idx] = p;
            pbuf[idx + HALF_N] = p;
        }
    }
    if (threadIdx.x < 16) rowsum[blockIdx.x * 16 + threadIdx.x] = 0.0f;
    if (blockIdx.x == 0 && threadIdx.x == 0) *done = 0u;
}

// ---- kernel 2: SYMMETRY-HALVED fp8 sim GEMM + exp rowsum + finalize --------
// sim is symmetric: strip (rg, cv) with cv > q(=rg>>2) is computed once and
// reduced BOTH ways: row-sums (as before) and column-sums (= transposed
// element's row contribution). Diagonal strip (cv==q) starts at its 64x64
// diagonal sub-block (row-only for those 4 steps, both after; earlier steps
// are covered by other diagonal strips' col-sums). Work: 2112 strips vs 4096.
// Body = R14/R16's proven absmax-0 code.
__global__ __launch_bounds__(256, 2) void k_gemm(
    const char* __restrict__ packA, const char* __restrict__ packB,
    float* __restrict__ rowsum, const float* __restrict__ pbuf,
    unsigned int* __restrict__ done, float* __restrict__ out)
{
    const int wave = threadIdx.x >> 6;
    const int lane = threadIdx.x & 63;
    const int qrow = lane >> 4, lcol = lane & 15;

    // ---- triangle strip decode: strips per q-group = 4*(32-q), offset
    //      off(q) = 130q - 2q^2 (q = rg>>2; cv in [q,32)) ----
    const int s_id = blockIdx.x * 4 + wave;          // 0..2111
    int q = (int)((130.0f - sqrtf(16900.0f - 8.0f * (float)s_id)) * 0.25f);
    while (130 * (q + 1) - 2 * (q + 1) * (q + 1) <= s_id) ++q;
    while (130 * q - 2 * q * q > s_id) --q;
    const int rem = s_id - (130 * q - 2 * q * q);
    const int w   = 32 - q;
    const int rg  = 4 * q + rem / w;                 // 64-row group, 0..127
    const int cv  = q + rem % w;                     // 256-col split, q..31
    const int diag = (cv == q);
    const int d0   = diag ? ((rg & 3) * 4) : 0;      // first step to compute

    // A fragments: 16 coalesced 512 B loads (rows rg*64..+63, all K)
    long afrag[4][4];
    #pragma unroll
    for (int mi = 0; mi < 4; ++mi)
        #pragma unroll
        for (int ks = 0; ks < 4; ++ks)
            afrag[mi][ks] = *(const long*)(packA
                + (size_t)(rg * 4 + mi) * 2048 + ks * 512 + lane * 8);

    float rsum[4][4];
    #pragma unroll
    for (int mi = 0; mi < 4; ++mi)
        #pragma unroll
        for (int r = 0; r < 4; ++r) rsum[mi][r] = 0.0f;

    const char* Bb = packB + (size_t)(cv * 16) * 2048 + lane * 8;

    #pragma unroll 4
    for (int s = d0; s < 16; ++s) {                  // 16-col steps
        const char* bp = Bb + (size_t)s * 2048;
        long bfrag[4];
        #pragma unroll
        for (int ks = 0; ks < 4; ++ks)
            bfrag[ks] = *(const long*)(bp + ks * 512);

        f32x4 acc[4];
        const f32x4 zero = {0.0f, 0.0f, 0.0f, 0.0f};
        #pragma unroll
        for (int mi = 0; mi < 4; ++mi) acc[mi] = zero;
        #pragma unroll
        for (int ks = 0; ks < 4; ++ks)
            #pragma unroll
            for (int mi = 0; mi < 4; ++mi)
                acc[mi] = __builtin_amdgcn_mfma_f32_16x16x32_fp8_fp8(
                    afrag[mi][ks], bfrag[ks], acc[mi], 0, 0, 0);

        // exp once; accumulate row-sums always, col-sums when off-diagonal
        float cs = 0.0f;
        #pragma unroll
        for (int mi = 0; mi < 4; ++mi)
            #pragma unroll
            for (int r = 0; r < 4; ++r) {
                const float e = __builtin_amdgcn_exp2f(acc[mi][r]);
                rsum[mi][r] += e;
                cs += e;
            }
        if (!diag || s >= d0 + 4) {     // wave-uniform branch
            cs += __shfl_xor(cs, 16, 64);
            cs += __shfl_xor(cs, 32, 64);
            if (qrow == 0)
                atomicAdd(&rowsum[cv * 256 + s * 16 + lcol], cs);
        }
    }

    // row-direction reduction over the 16 col-lanes, one atomic per row
    #pragma unroll
    for (int mi = 0; mi < 4; ++mi)
        #pragma unroll
        for (int r = 0; r < 4; ++r) {
            float v = rsum[mi][r];
            v += __shfl_xor(v, 1, 64);
            v += __shfl_xor(v, 2, 64);
            v += __shfl_xor(v, 4, 64);
            v += __shfl_xor(v, 8, 64);
            if (lcol == 0)
                atomicAdd(&rowsum[rg * 64 + mi * 16 + qrow * 4 + r], v);
        }

    // ---- last-block finalize; no producer-side fence (R11-R16 validated) ---
    __syncthreads();            // compiler drains vmcnt(0) before s_barrier
    __shared__ int is_last;
    if (threadIdx.x == 0) {
        unsigned old = __hip_atomic_fetch_add(done, 1u, __ATOMIC_RELAXED,
                                              __HIP_MEMORY_SCOPE_AGENT);
        is_last = (old == GBLK - 1);
    }
    __syncthreads();
    if (!is_last) return;
    __threadfence();            // acquire side only, once

    // loss_k = (log2(rowsum_k + 2^(p*C1)) - p*C1) * ln2   [v_log_f32 is LOG2]
    float lsum = 0.0f;
    for (int r = threadIdx.x; r < NROWS; r += 256) {
        float rs = __hip_atomic_load(&rowsum[r], __ATOMIC_RELAXED, __HIP_MEMORY_SCOPE_AGENT);
        float pc = pbuf[r] * C1;
        float S  = rs + __builtin_amdgcn_exp2f(pc);
        lsum += (__builtin_amdgcn_logf(S) - pc) * LN2;
    }
    #pragma unroll
    for (int m = 32; m >= 1; m >>= 1) lsum += __shfl_xor(lsum, m, 64);
    __shared__ float part[4];
    if (lane == 0) part[wave] = lsum;
    __syncthreads();
    if (threadIdx.x == 0)
        out[0] = (part[0] + part[1] + part[2] + part[3]) * (1.0f / (float)NROWS);
}

extern "C" void kernel_launch(void* const* d_in, const int* in_sizes, int n_in,
                              void* d_out, int out_size, void* d_ws, size_t ws_size,
                              hipStream_t stream)
{
    const float* zi = (const float*)d_in[0];
    const float* zj = (const float*)d_in[1];
    float* out = (float*)d_out;

    // ws: packA 1MB | packB 1MB | rowsum f32[8192] | pbuf f32[8192] | done
    char*  packA  = (char*)d_ws;
    char*  packB  = packA + (size_t)NROWS * 128;
    float* rowsum = (float*)(packB + (size_t)NROWS * 128);
    float* pbuf   = rowsum + NROWS;
    unsigned int* done = (unsigned int*)(pbuf + NROWS);

    k_normalize<<<NROWS / 16, 256, 0, stream>>>(zi, zj, packA, packB, rowsum, pbuf, done);
    k_gemm<<<GBLK, 256, 0, stream>>>(packA, packB, rowsum, pbuf, done, out);
}